// Round 18
// baseline (154.272 us; speedup 1.0000x reference)
//
#include <hip/hip_runtime.h>
#include <stdint.h>

typedef unsigned short u16;
typedef __attribute__((ext_vector_type(8))) short short8;
typedef __attribute__((ext_vector_type(4))) float f32x4;

#define DI __device__ __forceinline__

constexpr int S_LEN = 2048;
constexpr float LOG2E = 1.44269504088896f;
constexpr float SC = 0.125f * 1.44269504088896f;  // qk scale * log2(e)

DI float bf2f(u16 u) { union { uint32_t i; float f; } v; v.i = ((uint32_t)u) << 16; return v.f; }
DI u16 f2bf(float f) {
  union { float f; uint32_t i; } v; v.f = f;
  return (u16)((v.i + 0x7FFFu + ((v.i >> 16) & 1u)) >> 16);  // RNE
}
DI uint32_t cvtpk(float lo, float hi) {
  uint32_t r;
  asm("v_cvt_pk_bf16_f32 %0, %1, %2" : "=v"(r) : "v"(lo), "v"(hi));
  return r;
}
DI float exp2r(float x) {  // raw v_exp_f32 (2^x); avoids OCML range-check bloat
  float r;
  asm("v_exp_f32 %0, %1" : "=v"(r) : "v"(x));
  return r;
}

// async global->LDS, 16B per lane. LDS dest must be linear in lane order.
DI void cp16(const void* g, void* l) {
  auto gp = reinterpret_cast<const __attribute__((address_space(1))) uint32_t*>(
      reinterpret_cast<uintptr_t>(g));
  auto lp = reinterpret_cast<__attribute__((address_space(3))) uint32_t*>(
      reinterpret_cast<uintptr_t>(l));
  __builtin_amdgcn_global_load_lds(gp, lp, 16, 0, 0);
}

DI f32x4 mfma16(short8 a, short8 b, f32x4 c) {
  return __builtin_amdgcn_mfma_f32_16x16x32_bf16(a, b, c, 0, 0, 0);
}

// K-row permutation within a 64-row tile: LDS row rl holds global row perm(rl).
DI int permk(int rl) {
  return ((rl >> 5) & 1) * 32 + ((rl >> 2) & 3) * 8 + ((rl >> 4) & 1) * 4 + (rl & 3);
}

// ---------------- fused prep: converts + weight transposes ----------------
// blocks [0,4096): hidden fp32->bf16; [4096,12288): bias fp32->bf16*log2e;
// [12288,16384): weight transposes (96 col-tiles Wqkv, 32 col-tiles Wo) x 32.
__global__ __launch_bounds__(256) void k_prep(const float* __restrict__ hs,
                                              u16* __restrict__ h_bf,
                                              const float* __restrict__ bias,
                                              u16* __restrict__ biasbf,
                                              const float* __restrict__ Wqkv,
                                              u16* __restrict__ wqkvT,
                                              const float* __restrict__ Wo,
                                              u16* __restrict__ woT) {
  int bid = blockIdx.x;
  int tid = threadIdx.x;
  if (bid < 4096) {
    int i = bid * 256 + tid;
    float4 v = ((const float4*)hs)[i];
    ushort4 o = { f2bf(v.x), f2bf(v.y), f2bf(v.z), f2bf(v.w) };
    ((ushort4*)h_bf)[i] = o;
    return;
  }
  if (bid < 12288) {
    int i = (bid - 4096) * 256 + tid;
    float4 v = ((const float4*)bias)[i];
    ushort4 o = { f2bf(v.x * LOG2E), f2bf(v.y * LOG2E),
                  f2bf(v.z * LOG2E), f2bf(v.w * LOG2E) };
    ((ushort4*)biasbf)[i] = o;
    return;
  }
  __shared__ float t[32][33];
  int tt = bid - 12288;
  int bx = tt & 127, by = tt >> 7;
  const float* in;
  u16* out;
  int C;
  if (bx < 96) { in = Wqkv; out = wqkvT; C = 3072; }
  else         { bx -= 96; in = Wo; out = woT; C = 1024; }
  constexpr int R = 1024;
  int tx = tid & 31, ty = tid >> 5;
  int c0 = bx * 32, r0 = by * 32;
#pragma unroll
  for (int k = 0; k < 4; k++)
    t[ty + 8 * k][tx] = in[(size_t)(r0 + ty + 8 * k) * C + c0 + tx];
  __syncthreads();
#pragma unroll
  for (int k = 0; k < 4; k++)
    out[(size_t)(c0 + ty + 8 * k) * R + r0 + tx] = f2bf(t[tx][ty + 8 * k]);
}

// ---------------- GEMM: C[M][N] = A[M][K] * Bt[N][K]^T + bias ----------------
// BK=64, XOR-swizzled LDS (pre-swizzled global source), BN=128.
// WM = waves in M (2 -> 2x2 wave grid, each thread spans 64 cols, NJ=4;
//                  1 -> 1x4 wave grid, NJ=2). RoPE epilogue requires WM=2.
// QKV=1: cols<2048 get RoPE + store to qkv; cols>=2048 are V, stored
// TRANSPOSED to vtg[bh][d][s] (vectorized ushort4 over the row-quad).
template <int BM, int WM, int STORE_F32, int QKV>
__global__ __launch_bounds__(256) void k_gemm(const u16* __restrict__ A,
                                              const u16* __restrict__ Bt,
                                              const float* __restrict__ bias,
                                              void* __restrict__ Cout,
                                              u16* __restrict__ vtg,
                                              const float* __restrict__ cosb,
                                              const float* __restrict__ sinb,
                                              int N, int K, int nbx) {
  constexpr int NJ = 2 * WM;            // cols per thread / 16
  constexpr int MI = BM / WM / 16;      // row fragments per wave
  __shared__ u16 Al[BM * 64];
  __shared__ u16 Bl[128 * 64];
  int nwg = gridDim.x;
  int per = nwg >> 3;
  int id = blockIdx.x;
  int sid = (id & 7) * per + (id >> 3);     // XCD-aware swizzle (nwg % 8 == 0)
  int bx = sid % nbx, by = sid / nbx;
  int row0 = by * BM, col0 = bx * 128;
  int tid = threadIdx.x;
  int lane = tid & 63, wave = tid >> 6;
  int lg = lane >> 4, lc = lane & 15;
  int wroff = (WM == 2) ? (wave >> 1) * (BM / 2) : 0;
  int wcoff = (WM == 2) ? (wave & 1) * 64 : wave * 32;
  int srow = tid >> 3, sseg = tid & 7;
  int sw = (sseg ^ (srow & 7)) * 8;         // pre-swizzled source segment
  const u16* ga = A + (size_t)(row0 + srow) * K + sw;
  const u16* gb = Bt + (size_t)(col0 + srow) * K + sw;
  f32x4 acc[MI][NJ] = {};
  for (int ko = 0; ko < K; ko += 64) {
#pragma unroll
    for (int p = 0; p < BM / 32; p++)
      cp16(ga + (size_t)p * 32 * K + ko, Al + tid * 8 + p * 2048);
#pragma unroll
    for (int p = 0; p < 4; p++)
      cp16(gb + (size_t)p * 32 * K + ko, Bl + tid * 8 + p * 2048);
    __syncthreads();
#pragma unroll
    for (int kk = 0; kk < 2; kk++) {
      short8 af[MI], bf[NJ];
#pragma unroll
      for (int i = 0; i < MI; i++) {
        int row = wroff + i * 16 + lc;
        af[i] = *(const short8*)&Al[row * 64 + (((kk * 4 + lg) ^ (row & 7)) * 8)];
      }
#pragma unroll
      for (int j = 0; j < NJ; j++) {
        int row = wcoff + j * 16 + lc;
        bf[j] = *(const short8*)&Bl[row * 64 + (((kk * 4 + lg) ^ (row & 7)) * 8)];
      }
#pragma unroll
      for (int i = 0; i < MI; i++)
#pragma unroll
        for (int j = 0; j < NJ; j++) acc[i][j] = mfma16(af[i], bf[j], acc[i][j]);
    }
    __syncthreads();
  }
  int cbase = col0 + wcoff + lc;
  float bv[NJ];
#pragma unroll
  for (int j = 0; j < NJ; j++) bv[j] = bias[cbase + j * 16];

  if constexpr (QKV) {
    if (col0 >= 2048) {
      // V columns: transposed store to vtg[bh][d][s], 4 consecutive s/thread
#pragma unroll
      for (int i = 0; i < MI; i++) {
        int r = row0 + wroff + i * 16 + lg * 4;
        int bq = r >> 11, s0 = r & 2047;
#pragma unroll
        for (int j = 0; j < NJ; j++) {
          int c = cbase + j * 16 - 2048;
          int h = c >> 6, d = c & 63;
          ushort4 o4 = { f2bf(acc[i][j][0] + bv[j]), f2bf(acc[i][j][1] + bv[j]),
                         f2bf(acc[i][j][2] + bv[j]), f2bf(acc[i][j][3] + bv[j]) };
          *(ushort4*)&vtg[(size_t)(bq * 16 + h) * 131072 + (size_t)d * 2048 + s0] = o4;
        }
      }
      return;
    }
  }
#pragma unroll
  for (int i = 0; i < MI; i++) {
    int r = row0 + wroff + i * 16 + lg * 4;
#pragma unroll
    for (int q = 0; q < 4; q++) {
      float v[NJ];
#pragma unroll
      for (int j = 0; j < NJ; j++) v[j] = acc[i][j][q] + bv[j];
      if constexpr (QKV) {
        static_assert(!QKV || NJ == 4, "RoPE pairing needs 64-col thread span");
        int s = (r + q) & 2047;
        const float* cb = cosb + s * 64 + lc;
        const float* sb = sinb + s * 64 + lc;
#pragma unroll
        for (int jp = 0; jp < 2; jp++) {
          float cl = cb[jp * 16], sl = sb[jp * 16];
          float ch = cb[jp * 16 + 32], sh = sb[jp * 16 + 32];
          float x1 = v[jp], x2 = v[jp + 2];
          v[jp] = x1 * cl - x2 * sl;
          v[jp + 2] = x2 * ch + x1 * sh;
        }
      }
#pragma unroll
      for (int j = 0; j < NJ; j++) {
        if constexpr (STORE_F32)
          ((float*)Cout)[(size_t)(r + q) * N + cbase + j * 16] = v[j];
        else
          ((u16*)Cout)[(size_t)(r + q) * N + cbase + j * 16] = f2bf(v[j]);
      }
    }
  }
}

// ---------------- fused flash attention, P-in-registers ----------------
DI float sm_pa(const f32x4 st[4], const short8* bc, short8 pa[2]) {
  float acc = 0.f;
  uint32_t w[4][2];
#pragma unroll
  for (int j = 0; j < 4; j++) {
    int base = (j & 1) * 4;
    float b0 = bf2f((u16)(j < 2 ? bc[0][base + 0] : bc[1][base + 0]));
    float b1 = bf2f((u16)(j < 2 ? bc[0][base + 1] : bc[1][base + 1]));
    float b2 = bf2f((u16)(j < 2 ? bc[0][base + 2] : bc[1][base + 2]));
    float b3 = bf2f((u16)(j < 2 ? bc[0][base + 3] : bc[1][base + 3]));
    float e0 = exp2r(st[j][0] * SC + b0);
    float e1 = exp2r(st[j][1] * SC + b1);
    float e2 = exp2r(st[j][2] * SC + b2);
    float e3 = exp2r(st[j][3] * SC + b3);
    acc += (e0 + e1) + (e2 + e3);
    w[j][0] = cvtpk(e0, e1);
    w[j][1] = cvtpk(e2, e3);
  }
  union { short8 s; uint32_t u[4]; } p0, p1;
  p0.u[0] = w[0][0]; p0.u[1] = w[0][1]; p0.u[2] = w[1][0]; p0.u[3] = w[1][1];
  p1.u[0] = w[2][0]; p1.u[1] = w[2][1]; p1.u[2] = w[3][0]; p1.u[3] = w[3][1];
  pa[0] = p0.s;
  pa[1] = p1.s;
  return acc;
}

DI void attn_store(u16* __restrict__ ctx, const f32x4 o[4], float lsumT,
                   size_t rowbase, int hcol, int lg, int lc) {
  float rinv[4];
#pragma unroll
  for (int r = 0; r < 4; r++) rinv[r] = 1.0f / __shfl(lsumT, lg * 4 + r);
#pragma unroll
  for (int j = 0; j < 4; j++)
#pragma unroll
    for (int r = 0; r < 4; r++)
      ctx[(rowbase + lg * 4 + r) * 1024 + hcol + j * 16 + lc] =
          f2bf(o[j][r] * rinv[r]);
}

// 32 q-rows per wave (2 sets of 16 sharing all K/V fragment reads);
// 2-wave (128-thread) blocks, 64 q-rows each; 1024 blocks = 4/CU.
// Smaller barrier groups -> more independent phase-offset streams per CU.
// bf16 bias (pre-scaled by LOG2E), register-prefetched; softmax/PV interleave.
__global__ __launch_bounds__(128, 4) void k_attn(const u16* __restrict__ qkv,
                                                 const u16* __restrict__ biasl2,
                                                 const u16* __restrict__ vtg,
                                                 u16* __restrict__ ctx) {
  __shared__ u16 Kl[2][4096];  // [64 k(permuted)][64 d], seg XOR-swizzled
  __shared__ u16 Vl[2][4096];  // [64 d][64 k], seg XOR-swizzled
  constexpr int nkt = 32;
  int id = blockIdx.x;
  int idx = id >> 3;                  // 0..127
  int bh = (id & 7) * 4 + (idx & 3);  // 4 heads per XCD
  int qt = idx >> 2;                  // 0..31 (64 q-rows each)
  int b = bh >> 4, h = bh & 15;
  int tid = threadIdx.x, lane = tid & 63, wave = tid >> 6;  // wave in {0,1}
  int lg = lane >> 4, lc = lane & 15;
  int q0 = qt * 64 + wave * 32;

  // Q fragments: 2 sets of 16 rows per wave
  const u16* qb = qkv + (size_t)(b * S_LEN + q0 + lc) * 3072 + h * 64 + lg * 8;
  short8 qf[2][2];
#pragma unroll
  for (int s = 0; s < 2; s++) {
    qf[s][0] = *(const short8*)(qb + (size_t)s * 16 * 3072);
    qf[s][1] = *(const short8*)(qb + (size_t)s * 16 * 3072 + 32);
  }

  // staging pointers (128 threads x 4 rows each): LDS row rl <- K global row
  // permk(rl); V natural. dest u16 offset = rl*64 + sseg*8 (same layout as
  // the 256-thread version, so read-side indexing is unchanged).
  int srow = tid >> 3, sseg = tid & 7;  // srow in [0,16)
  const u16* kst[4];
  const u16* vst[4];
#pragma unroll
  for (int p = 0; p < 4; p++) {
    int rl = srow + 16 * p;
    int sw = (sseg ^ (rl & 7)) * 8;
    kst[p] = qkv + (size_t)(b * S_LEN + permk(rl)) * 3072 + 1024 + h * 64 + sw;
    vst[p] = vtg + (size_t)bh * 64 * 2048 + (size_t)rl * 2048 + sw;
  }

  // bias pointers (per q-set); always point at the NEXT tile to load
  const u16* bp0 = biasl2 + ((size_t)b * S_LEN + q0 + lc) * 2048 + lg * 8;
  const u16* bp1 = bp0 + (size_t)16 * 2048;

  f32x4 o0[4] = {}, o1[4] = {};
  float lsum0 = 0.f, lsum1 = 0.f;

  // prologue: stage tile 0 into buf 0; load bias(0) into register set A
#pragma unroll
  for (int p = 0; p < 4; p++) {
    cp16(kst[p], (u16*)&Kl[0][0] + p * 1024 + tid * 8);
    cp16(vst[p], (u16*)&Vl[0][0] + p * 1024 + tid * 8);
    kst[p] += (size_t)64 * 3072;
    vst[p] += 64;
  }
  short8 bA[4], bB[4];
  bA[0] = *(const short8*)bp0;
  bA[1] = *(const short8*)(bp0 + 32);
  bA[2] = *(const short8*)bp1;
  bA[3] = *(const short8*)(bp1 + 32);
  bp0 += 64;
  bp1 += 64;
  __syncthreads();

  // one k-tile: uses bias regs bc (this tile), prefetches next tile's into bn
  auto tile = [&](int kt, int cur, const short8* bc, short8* bn) {
    if (kt < nkt - 1) {  // stage K/V for kt+1 + prefetch bias(kt+1) -> regs
#pragma unroll
      for (int p = 0; p < 4; p++) {
        cp16(kst[p], (u16*)&Kl[cur ^ 1][0] + p * 1024 + tid * 8);
        cp16(vst[p], (u16*)&Vl[cur ^ 1][0] + p * 1024 + tid * 8);
        kst[p] += (size_t)64 * 3072;
        vst[p] += 64;
      }
      bn[0] = *(const short8*)bp0;
      bn[1] = *(const short8*)(bp0 + 32);
      bn[2] = *(const short8*)bp1;
      bn[3] = *(const short8*)(bp1 + 32);
      bp0 += 64;
      bp1 += 64;
    }
    // St = K*Q for both q-sets; K fragments loaded once, used twice
    f32x4 st0[4] = {}, st1[4] = {};
    __builtin_amdgcn_s_setprio(1);
#pragma unroll
    for (int kk = 0; kk < 2; kk++) {
      short8 kf[4];
#pragma unroll
      for (int j = 0; j < 4; j++) {
        int row = j * 16 + lc;
        kf[j] = *(const short8*)&Kl[cur][row * 64 + (((kk * 4 + lg) ^ (row & 7)) * 8)];
      }
#pragma unroll
      for (int j = 0; j < 4; j++) {
        st0[j] = mfma16(kf[j], qf[0][kk], st0[j]);
        st1[j] = mfma16(kf[j], qf[1][kk], st1[j]);
      }
    }
    __builtin_amdgcn_s_setprio(0);
    // V fragments for both kk slices (shared by both q-sets)
    short8 vf0[4], vf1[4];
#pragma unroll
    for (int j = 0; j < 4; j++) {
      int row = j * 16 + lc;
      vf0[j] = *(const short8*)&Vl[cur][row * 64 + ((lg ^ (row & 7)) * 8)];
      vf1[j] = *(const short8*)&Vl[cur][row * 64 + (((4 + lg) ^ (row & 7)) * 8)];
    }
    // set0 softmax -> PV(kk=0) -> set1 softmax (VALU overlaps set0 MFMA) -> rest
    short8 pa0[2], pa1[2];
    lsum0 += sm_pa(st0, bc, pa0);
    __builtin_amdgcn_s_setprio(1);
#pragma unroll
    for (int j = 0; j < 4; j++) o0[j] = mfma16(pa0[0], vf0[j], o0[j]);
    __builtin_amdgcn_s_setprio(0);
    lsum1 += sm_pa(st1, bc + 2, pa1);
    __builtin_amdgcn_s_setprio(1);
#pragma unroll
    for (int j = 0; j < 4; j++) o1[j] = mfma16(pa1[0], vf0[j], o1[j]);
#pragma unroll
    for (int j = 0; j < 4; j++) o0[j] = mfma16(pa0[1], vf1[j], o0[j]);
#pragma unroll
    for (int j = 0; j < 4; j++) o1[j] = mfma16(pa1[1], vf1[j], o1[j]);
    __builtin_amdgcn_s_setprio(0);
    __syncthreads();  // drains this tile's prefetch (K/V + bias in flight)
  };

  for (int kt = 0; kt < nkt; kt += 2) {
    tile(kt, 0, bA, bB);
    tile(kt + 1, 1, bB, bA);
  }

  float t0 = lsum0;
  t0 += __shfl_xor(t0, 16);
  t0 += __shfl_xor(t0, 32);
  float t1 = lsum1;
  t1 += __shfl_xor(t1, 16);
  t1 += __shfl_xor(t1, 32);
  size_t rowbase = (size_t)b * S_LEN + q0;
  attn_store(ctx, o0, t0, rowbase, h * 64, lg, lc);
  attn_store(ctx, o1, t1, rowbase + 16, h * 64, lg, lc);
}

extern "C" void kernel_launch(void* const* d_in, const int* in_sizes, int n_in,
                              void* d_out, int out_size, void* d_ws, size_t ws_size,
                              hipStream_t stream) {
  (void)in_sizes; (void)n_in; (void)out_size; (void)ws_size;
  const float* hs   = (const float*)d_in[0];
  const float* bias = (const float*)d_in[1];
  const float* cosb = (const float*)d_in[2];
  const float* sinb = (const float*)d_in[3];
  const float* Wqkv = (const float*)d_in[4];
  const float* bqkv = (const float*)d_in[5];
  const float* Wo   = (const float*)d_in[6];
  const float* bo   = (const float*)d_in[7];
  float* out = (float*)d_out;
  char* ws = (char*)d_ws;
  u16* h_bf   = (u16*)(ws + 0);          //  8,388,608 B  hidden bf16 [4096][1024]
  u16* wqkvT  = (u16*)(ws + 8388608);    //  6,291,456 B  Wqkv^T bf16 [3072][1024]
  u16* woT    = (u16*)(ws + 14680064);   //  2,097,152 B  Wo^T bf16 [1024][1024]
  u16* biasbf = (u16*)(ws + 16777216);   // 16,777,216 B  bias*log2e bf16 [2][2048][2048]
  u16* qkv    = (u16*)(ws + 33554432);   // 25,165,824 B  qkv bf16 [4096][3072] (v third unused)
  u16* vtg    = (u16*)(ws + 58720256);   //  8,388,608 B  V^T bf16 [32][64][2048]
  u16* ctxb   = (u16*)(ws + 67108864);   //  8,388,608 B  ctx bf16 [4096][1024]

  k_prep<<<16384, 256, 0, stream>>>(hs, h_bf, bias, biasbf, Wqkv, wqkvT, Wo, woT);
  k_gemm<64, 2, 0, 1><<<1536, 256, 0, stream>>>(h_bf, wqkvT, bqkv, qkv, vtg,
                                                cosb, sinb, 3072, 1024, 24);
  k_attn<<<1024, 128, 0, stream>>>(qkv, biasbf, vtg, ctxb);
  k_gemm<32, 2, 1, 0><<<1024, 256, 0, stream>>>(ctxb, woT, bo, out, nullptr,
                                                nullptr, nullptr, 1024, 1024, 8);
}

// Round 19
// 130.419 us; speedup vs baseline: 1.1829x; 1.1829x over previous
//
#include <hip/hip_runtime.h>
#include <stdint.h>

typedef unsigned short u16;
typedef __attribute__((ext_vector_type(8))) short short8;
typedef __attribute__((ext_vector_type(4))) float f32x4;

#define DI __device__ __forceinline__

constexpr int S_LEN = 2048;
constexpr float LOG2E = 1.44269504088896f;
constexpr float SC = 0.125f * 1.44269504088896f;  // qk scale * log2(e)

DI float bf2f(u16 u) { union { uint32_t i; float f; } v; v.i = ((uint32_t)u) << 16; return v.f; }
DI u16 f2bf(float f) {
  union { float f; uint32_t i; } v; v.f = f;
  return (u16)((v.i + 0x7FFFu + ((v.i >> 16) & 1u)) >> 16);  // RNE
}
DI uint32_t cvtpk(float lo, float hi) {
  uint32_t r;
  asm("v_cvt_pk_bf16_f32 %0, %1, %2" : "=v"(r) : "v"(lo), "v"(hi));
  return r;
}
DI float exp2r(float x) {  // raw v_exp_f32 (2^x); avoids OCML range-check bloat
  float r;
  asm("v_exp_f32 %0, %1" : "=v"(r) : "v"(x));
  return r;
}

// async global->LDS, 16B per lane. LDS dest must be linear in lane order.
DI void cp16(const void* g, void* l) {
  auto gp = reinterpret_cast<const __attribute__((address_space(1))) uint32_t*>(
      reinterpret_cast<uintptr_t>(g));
  auto lp = reinterpret_cast<__attribute__((address_space(3))) uint32_t*>(
      reinterpret_cast<uintptr_t>(l));
  __builtin_amdgcn_global_load_lds(gp, lp, 16, 0, 0);
}

DI f32x4 mfma16(short8 a, short8 b, f32x4 c) {
  return __builtin_amdgcn_mfma_f32_16x16x32_bf16(a, b, c, 0, 0, 0);
}

// K-row permutation within a 64-row tile: LDS row rl holds global row perm(rl).
DI int permk(int rl) {
  return ((rl >> 5) & 1) * 32 + ((rl >> 2) & 3) * 8 + ((rl >> 4) & 1) * 4 + (rl & 3);
}

// ---------------- fused prep: converts + weight transposes ----------------
// blocks [0,4096): hidden fp32->bf16; [4096,12288): bias fp32->bf16*log2e;
// [12288,16384): weight transposes (96 col-tiles Wqkv, 32 col-tiles Wo) x 32.
__global__ __launch_bounds__(256) void k_prep(const float* __restrict__ hs,
                                              u16* __restrict__ h_bf,
                                              const float* __restrict__ bias,
                                              u16* __restrict__ biasbf,
                                              const float* __restrict__ Wqkv,
                                              u16* __restrict__ wqkvT,
                                              const float* __restrict__ Wo,
                                              u16* __restrict__ woT) {
  int bid = blockIdx.x;
  int tid = threadIdx.x;
  if (bid < 4096) {
    int i = bid * 256 + tid;
    float4 v = ((const float4*)hs)[i];
    ushort4 o = { f2bf(v.x), f2bf(v.y), f2bf(v.z), f2bf(v.w) };
    ((ushort4*)h_bf)[i] = o;
    return;
  }
  if (bid < 12288) {
    int i = (bid - 4096) * 256 + tid;
    float4 v = ((const float4*)bias)[i];
    ushort4 o = { f2bf(v.x * LOG2E), f2bf(v.y * LOG2E),
                  f2bf(v.z * LOG2E), f2bf(v.w * LOG2E) };
    ((ushort4*)biasbf)[i] = o;
    return;
  }
  __shared__ float t[32][33];
  int tt = bid - 12288;
  int bx = tt & 127, by = tt >> 7;
  const float* in;
  u16* out;
  int C;
  if (bx < 96) { in = Wqkv; out = wqkvT; C = 3072; }
  else         { bx -= 96; in = Wo; out = woT; C = 1024; }
  constexpr int R = 1024;
  int tx = tid & 31, ty = tid >> 5;
  int c0 = bx * 32, r0 = by * 32;
#pragma unroll
  for (int k = 0; k < 4; k++)
    t[ty + 8 * k][tx] = in[(size_t)(r0 + ty + 8 * k) * C + c0 + tx];
  __syncthreads();
#pragma unroll
  for (int k = 0; k < 4; k++)
    out[(size_t)(c0 + ty + 8 * k) * R + r0 + tx] = f2bf(t[tx][ty + 8 * k]);
}

// ---------------- GEMM: C[M][N] = A[M][K] * Bt[N][K]^T + bias ----------------
// BK=64, XOR-swizzled LDS (pre-swizzled global source), BN=128.
// WM = waves in M (2 -> 2x2 wave grid, each thread spans 64 cols, NJ=4;
//                  1 -> 1x4 wave grid, NJ=2). RoPE epilogue requires WM=2.
// QKV=1: cols<2048 get RoPE + store to qkv; cols>=2048 are V, stored
// TRANSPOSED to vtg[bh][d][s] (vectorized ushort4 over the row-quad).
template <int BM, int WM, int STORE_F32, int QKV>
__global__ __launch_bounds__(256) void k_gemm(const u16* __restrict__ A,
                                              const u16* __restrict__ Bt,
                                              const float* __restrict__ bias,
                                              void* __restrict__ Cout,
                                              u16* __restrict__ vtg,
                                              const float* __restrict__ cosb,
                                              const float* __restrict__ sinb,
                                              int N, int K, int nbx) {
  constexpr int NJ = 2 * WM;            // cols per thread / 16
  constexpr int MI = BM / WM / 16;      // row fragments per wave
  __shared__ u16 Al[BM * 64];
  __shared__ u16 Bl[128 * 64];
  int nwg = gridDim.x;
  int per = nwg >> 3;
  int id = blockIdx.x;
  int sid = (id & 7) * per + (id >> 3);     // XCD-aware swizzle (nwg % 8 == 0)
  int bx = sid % nbx, by = sid / nbx;
  int row0 = by * BM, col0 = bx * 128;
  int tid = threadIdx.x;
  int lane = tid & 63, wave = tid >> 6;
  int lg = lane >> 4, lc = lane & 15;
  int wroff = (WM == 2) ? (wave >> 1) * (BM / 2) : 0;
  int wcoff = (WM == 2) ? (wave & 1) * 64 : wave * 32;
  int srow = tid >> 3, sseg = tid & 7;
  int sw = (sseg ^ (srow & 7)) * 8;         // pre-swizzled source segment
  const u16* ga = A + (size_t)(row0 + srow) * K + sw;
  const u16* gb = Bt + (size_t)(col0 + srow) * K + sw;
  f32x4 acc[MI][NJ] = {};
  for (int ko = 0; ko < K; ko += 64) {
#pragma unroll
    for (int p = 0; p < BM / 32; p++)
      cp16(ga + (size_t)p * 32 * K + ko, Al + tid * 8 + p * 2048);
#pragma unroll
    for (int p = 0; p < 4; p++)
      cp16(gb + (size_t)p * 32 * K + ko, Bl + tid * 8 + p * 2048);
    __syncthreads();
#pragma unroll
    for (int kk = 0; kk < 2; kk++) {
      short8 af[MI], bf[NJ];
#pragma unroll
      for (int i = 0; i < MI; i++) {
        int row = wroff + i * 16 + lc;
        af[i] = *(const short8*)&Al[row * 64 + (((kk * 4 + lg) ^ (row & 7)) * 8)];
      }
#pragma unroll
      for (int j = 0; j < NJ; j++) {
        int row = wcoff + j * 16 + lc;
        bf[j] = *(const short8*)&Bl[row * 64 + (((kk * 4 + lg) ^ (row & 7)) * 8)];
      }
#pragma unroll
      for (int i = 0; i < MI; i++)
#pragma unroll
        for (int j = 0; j < NJ; j++) acc[i][j] = mfma16(af[i], bf[j], acc[i][j]);
    }
    __syncthreads();
  }
  int cbase = col0 + wcoff + lc;
  float bv[NJ];
#pragma unroll
  for (int j = 0; j < NJ; j++) bv[j] = bias[cbase + j * 16];

  if constexpr (QKV) {
    if (col0 >= 2048) {
      // V columns: transposed store to vtg[bh][d][s], 4 consecutive s/thread
#pragma unroll
      for (int i = 0; i < MI; i++) {
        int r = row0 + wroff + i * 16 + lg * 4;
        int bq = r >> 11, s0 = r & 2047;
#pragma unroll
        for (int j = 0; j < NJ; j++) {
          int c = cbase + j * 16 - 2048;
          int h = c >> 6, d = c & 63;
          ushort4 o4 = { f2bf(acc[i][j][0] + bv[j]), f2bf(acc[i][j][1] + bv[j]),
                         f2bf(acc[i][j][2] + bv[j]), f2bf(acc[i][j][3] + bv[j]) };
          *(ushort4*)&vtg[(size_t)(bq * 16 + h) * 131072 + (size_t)d * 2048 + s0] = o4;
        }
      }
      return;
    }
  }
#pragma unroll
  for (int i = 0; i < MI; i++) {
    int r = row0 + wroff + i * 16 + lg * 4;
#pragma unroll
    for (int q = 0; q < 4; q++) {
      float v[NJ];
#pragma unroll
      for (int j = 0; j < NJ; j++) v[j] = acc[i][j][q] + bv[j];
      if constexpr (QKV) {
        static_assert(!QKV || NJ == 4, "RoPE pairing needs 64-col thread span");
        int s = (r + q) & 2047;
        const float* cb = cosb + s * 64 + lc;
        const float* sb = sinb + s * 64 + lc;
#pragma unroll
        for (int jp = 0; jp < 2; jp++) {
          float cl = cb[jp * 16], sl = sb[jp * 16];
          float ch = cb[jp * 16 + 32], sh = sb[jp * 16 + 32];
          float x1 = v[jp], x2 = v[jp + 2];
          v[jp] = x1 * cl - x2 * sl;
          v[jp + 2] = x2 * ch + x1 * sh;
        }
      }
#pragma unroll
      for (int j = 0; j < NJ; j++) {
        if constexpr (STORE_F32)
          ((float*)Cout)[(size_t)(r + q) * N + cbase + j * 16] = v[j];
        else
          ((u16*)Cout)[(size_t)(r + q) * N + cbase + j * 16] = f2bf(v[j]);
      }
    }
  }
}

// ---------------- fused flash attention, P-in-registers ----------------
DI float sm_pa(const f32x4 st[4], const short8* bc, short8 pa[2]) {
  float acc = 0.f;
  uint32_t w[4][2];
#pragma unroll
  for (int j = 0; j < 4; j++) {
    int base = (j & 1) * 4;
    float b0 = bf2f((u16)(j < 2 ? bc[0][base + 0] : bc[1][base + 0]));
    float b1 = bf2f((u16)(j < 2 ? bc[0][base + 1] : bc[1][base + 1]));
    float b2 = bf2f((u16)(j < 2 ? bc[0][base + 2] : bc[1][base + 2]));
    float b3 = bf2f((u16)(j < 2 ? bc[0][base + 3] : bc[1][base + 3]));
    float e0 = exp2r(st[j][0] * SC + b0);
    float e1 = exp2r(st[j][1] * SC + b1);
    float e2 = exp2r(st[j][2] * SC + b2);
    float e3 = exp2r(st[j][3] * SC + b3);
    acc += (e0 + e1) + (e2 + e3);
    w[j][0] = cvtpk(e0, e1);
    w[j][1] = cvtpk(e2, e3);
  }
  union { short8 s; uint32_t u[4]; } p0, p1;
  p0.u[0] = w[0][0]; p0.u[1] = w[0][1]; p0.u[2] = w[1][0]; p0.u[3] = w[1][1];
  p1.u[0] = w[2][0]; p1.u[1] = w[2][1]; p1.u[2] = w[3][0]; p1.u[3] = w[3][1];
  pa[0] = p0.s;
  pa[1] = p1.s;
  return acc;
}

DI void attn_store(u16* __restrict__ ctx, const f32x4 o[4], float lsumT,
                   size_t rowbase, int hcol, int lg, int lc) {
  float rinv[4];
#pragma unroll
  for (int r = 0; r < 4; r++) rinv[r] = 1.0f / __shfl(lsumT, lg * 4 + r);
#pragma unroll
  for (int j = 0; j < 4; j++)
#pragma unroll
    for (int r = 0; r < 4; r++)
      ctx[(rowbase + lg * 4 + r) * 1024 + hcol + j * 16 + lc] =
          f2bf(o[j][r] * rinv[r]);
}

// 32 q-rows per wave (2 sets of 16 sharing all K/V fragment reads), 128/block;
// 512 blocks = 2/CU. bf16 bias (pre-scaled by LOG2E), register-prefetched.
// Tile body interleaves set1's softmax VALU between set0/set1 PV MFMA clusters.
__global__ __launch_bounds__(256, 2) void k_attn(const u16* __restrict__ qkv,
                                                 const u16* __restrict__ biasl2,
                                                 const u16* __restrict__ vtg,
                                                 u16* __restrict__ ctx) {
  __shared__ u16 Kl[2][4096];  // [64 k(permuted)][64 d], seg XOR-swizzled
  __shared__ u16 Vl[2][4096];  // [64 d][64 k], seg XOR-swizzled
  constexpr int nkt = 32;
  int id = blockIdx.x;
  int idx = id >> 3;
  int bh = (id & 7) * 4 + (idx & 3);  // 4 heads per XCD
  int qt = idx >> 2;                  // 0..15
  int b = bh >> 4, h = bh & 15;
  int tid = threadIdx.x, lane = tid & 63, wave = tid >> 6;
  int lg = lane >> 4, lc = lane & 15;
  int q0 = qt * 128 + wave * 32;

  // Q fragments: 2 sets of 16 rows per wave
  const u16* qb = qkv + (size_t)(b * S_LEN + q0 + lc) * 3072 + h * 64 + lg * 8;
  short8 qf[2][2];
#pragma unroll
  for (int s = 0; s < 2; s++) {
    qf[s][0] = *(const short8*)(qb + (size_t)s * 16 * 3072);
    qf[s][1] = *(const short8*)(qb + (size_t)s * 16 * 3072 + 32);
  }

  // staging pointers: LDS row rl <- K global row permk(rl); V natural
  int srow = tid >> 3, sseg = tid & 7;
  const u16* kst[2];
  const u16* vst[2];
#pragma unroll
  for (int p = 0; p < 2; p++) {
    int rl = srow + 32 * p;
    int sw = (sseg ^ (rl & 7)) * 8;
    kst[p] = qkv + (size_t)(b * S_LEN + permk(rl)) * 3072 + 1024 + h * 64 + sw;
    vst[p] = vtg + (size_t)bh * 64 * 2048 + (size_t)rl * 2048 + sw;
  }

  // bias pointers (per q-set); always point at the NEXT tile to load
  const u16* bp0 = biasl2 + ((size_t)b * S_LEN + q0 + lc) * 2048 + lg * 8;
  const u16* bp1 = bp0 + (size_t)16 * 2048;

  f32x4 o0[4] = {}, o1[4] = {};
  float lsum0 = 0.f, lsum1 = 0.f;

  // prologue: stage tile 0 into buf 0; load bias(0) into register set A
#pragma unroll
  for (int p = 0; p < 2; p++) {
    cp16(kst[p], (u16*)&Kl[0][0] + p * 2048 + tid * 8);
    cp16(vst[p], (u16*)&Vl[0][0] + p * 2048 + tid * 8);
    kst[p] += (size_t)64 * 3072;
    vst[p] += 64;
  }
  short8 bA[4], bB[4];
  bA[0] = *(const short8*)bp0;
  bA[1] = *(const short8*)(bp0 + 32);
  bA[2] = *(const short8*)bp1;
  bA[3] = *(const short8*)(bp1 + 32);
  bp0 += 64;
  bp1 += 64;
  __syncthreads();

  // one k-tile: uses bias regs bc (this tile), prefetches next tile's into bn
  auto tile = [&](int kt, int cur, const short8* bc, short8* bn) {
    if (kt < nkt - 1) {  // stage K/V for kt+1 + prefetch bias(kt+1) -> regs
#pragma unroll
      for (int p = 0; p < 2; p++) {
        cp16(kst[p], (u16*)&Kl[cur ^ 1][0] + p * 2048 + tid * 8);
        cp16(vst[p], (u16*)&Vl[cur ^ 1][0] + p * 2048 + tid * 8);
        kst[p] += (size_t)64 * 3072;
        vst[p] += 64;
      }
      bn[0] = *(const short8*)bp0;
      bn[1] = *(const short8*)(bp0 + 32);
      bn[2] = *(const short8*)bp1;
      bn[3] = *(const short8*)(bp1 + 32);
      bp0 += 64;
      bp1 += 64;
    }
    // St = K*Q for both q-sets; K fragments loaded once, used twice
    f32x4 st0[4] = {}, st1[4] = {};
    __builtin_amdgcn_s_setprio(1);
#pragma unroll
    for (int kk = 0; kk < 2; kk++) {
      short8 kf[4];
#pragma unroll
      for (int j = 0; j < 4; j++) {
        int row = j * 16 + lc;
        kf[j] = *(const short8*)&Kl[cur][row * 64 + (((kk * 4 + lg) ^ (row & 7)) * 8)];
      }
#pragma unroll
      for (int j = 0; j < 4; j++) {
        st0[j] = mfma16(kf[j], qf[0][kk], st0[j]);
        st1[j] = mfma16(kf[j], qf[1][kk], st1[j]);
      }
    }
    __builtin_amdgcn_s_setprio(0);
    // V fragments for both kk slices (shared by both q-sets)
    short8 vf0[4], vf1[4];
#pragma unroll
    for (int j = 0; j < 4; j++) {
      int row = j * 16 + lc;
      vf0[j] = *(const short8*)&Vl[cur][row * 64 + ((lg ^ (row & 7)) * 8)];
      vf1[j] = *(const short8*)&Vl[cur][row * 64 + (((4 + lg) ^ (row & 7)) * 8)];
    }
    // set0 softmax -> PV(kk=0) -> set1 softmax (VALU overlaps set0 MFMA) -> rest
    short8 pa0[2], pa1[2];
    lsum0 += sm_pa(st0, bc, pa0);
    __builtin_amdgcn_s_setprio(1);
#pragma unroll
    for (int j = 0; j < 4; j++) o0[j] = mfma16(pa0[0], vf0[j], o0[j]);
    __builtin_amdgcn_s_setprio(0);
    lsum1 += sm_pa(st1, bc + 2, pa1);
    __builtin_amdgcn_s_setprio(1);
#pragma unroll
    for (int j = 0; j < 4; j++) o1[j] = mfma16(pa1[0], vf0[j], o1[j]);
#pragma unroll
    for (int j = 0; j < 4; j++) o0[j] = mfma16(pa0[1], vf1[j], o0[j]);
#pragma unroll
    for (int j = 0; j < 4; j++) o1[j] = mfma16(pa1[1], vf1[j], o1[j]);
    __builtin_amdgcn_s_setprio(0);
    __syncthreads();  // drains this tile's prefetch (K/V + bias in flight)
  };

  for (int kt = 0; kt < nkt; kt += 2) {
    tile(kt, 0, bA, bB);
    tile(kt + 1, 1, bB, bA);
  }

  float t0 = lsum0;
  t0 += __shfl_xor(t0, 16);
  t0 += __shfl_xor(t0, 32);
  float t1 = lsum1;
  t1 += __shfl_xor(t1, 16);
  t1 += __shfl_xor(t1, 32);
  size_t rowbase = (size_t)b * S_LEN + q0;
  attn_store(ctx, o0, t0, rowbase, h * 64, lg, lc);
  attn_store(ctx, o1, t1, rowbase + 16, h * 64, lg, lc);
}

extern "C" void kernel_launch(void* const* d_in, const int* in_sizes, int n_in,
                              void* d_out, int out_size, void* d_ws, size_t ws_size,
                              hipStream_t stream) {
  (void)in_sizes; (void)n_in; (void)out_size; (void)ws_size;
  const float* hs   = (const float*)d_in[0];
  const float* bias = (const float*)d_in[1];
  const float* cosb = (const float*)d_in[2];
  const float* sinb = (const float*)d_in[3];
  const float* Wqkv = (const float*)d_in[4];
  const float* bqkv = (const float*)d_in[5];
  const float* Wo   = (const float*)d_in[6];
  const float* bo   = (const float*)d_in[7];
  float* out = (float*)d_out;
  char* ws = (char*)d_ws;
  u16* h_bf   = (u16*)(ws + 0);          //  8,388,608 B  hidden bf16 [4096][1024]
  u16* wqkvT  = (u16*)(ws + 8388608);    //  6,291,456 B  Wqkv^T bf16 [3072][1024]
  u16* woT    = (u16*)(ws + 14680064);   //  2,097,152 B  Wo^T bf16 [1024][1024]
  u16* biasbf = (u16*)(ws + 16777216);   // 16,777,216 B  bias*log2e bf16 [2][2048][2048]
  u16* qkv    = (u16*)(ws + 33554432);   // 25,165,824 B  qkv bf16 [4096][3072] (v third unused)
  u16* vtg    = (u16*)(ws + 58720256);   //  8,388,608 B  V^T bf16 [32][64][2048]
  u16* ctxb   = (u16*)(ws + 67108864);   //  8,388,608 B  ctx bf16 [4096][1024]

  k_prep<<<16384, 256, 0, stream>>>(hs, h_bf, bias, biasbf, Wqkv, wqkvT, Wo, woT);
  k_gemm<64, 2, 0, 1><<<1536, 256, 0, stream>>>(h_bf, wqkvT, bqkv, qkv, vtg,
                                                cosb, sinb, 3072, 1024, 24);
  k_attn<<<512, 256, 0, stream>>>(qkv, biasbf, vtg, ctxb);
  k_gemm<32, 2, 1, 0><<<1024, 256, 0, stream>>>(ctxb, woT, bo, out, nullptr,
                                                nullptr, nullptr, 1024, 1024, 8);
}